// Round 3
// baseline (606.209 us; speedup 1.0000x reference)
//
#include <hip/hip_runtime.h>
#include <stdint.h>
#include <stddef.h>

typedef __bf16 bf16;
typedef __bf16 bf16x4 __attribute__((ext_vector_type(4)));
typedef __bf16 bf16x8 __attribute__((ext_vector_type(8)));
typedef float f32x4 __attribute__((ext_vector_type(4)));

#define BATCH 4
#define G_LEN 1024
#define S_LEN 4096
#define DM 512
#define NH 8
#define DK 64

__device__ __forceinline__ f32x4 mfma16(bf16x8 a, bf16x8 b, f32x4 c) {
    return __builtin_amdgcn_mfma_f32_16x16x32_bf16(a, b, c, 0, 0, 0);
}

// ---------------------------------------------------------------------------
// cis dtype detection (bool vs int32) — see round 1 notes. flag=1 -> bytes.
// ---------------------------------------------------------------------------
__global__ void detect_cis(const unsigned char* __restrict__ cis, int* __restrict__ flag) {
    int any = 0;
    for (int i = threadIdx.x; i < 16384; i += 64)
        any |= cis[4 * i + 1];
    #pragma unroll
    for (int off = 1; off < 64; off <<= 1) any |= __shfl_xor(any, off);
    if (threadIdx.x == 0) flag[0] = (any != 0) ? 1 : 0;
}

// ---------------------------------------------------------------------------
// GEMM: Y[m][n] = sum_k X[m][k]*W[n][k] + bias[n] (+ shift[batch(m)][n])
// (unchanged from round 2 — correctness-proven; revisit if profile says so)
// ---------------------------------------------------------------------------
template<int A_IS_BF16, int TRANS_OUT, int OUT_F32, int ROWS_PER_B>
__global__ __launch_bounds__(256) void gemm_proj(
    const void* __restrict__ Ap, const float* __restrict__ W,
    const float* __restrict__ bias, const float* __restrict__ shift,
    void* __restrict__ Out)
{
    __shared__ bf16 As[64][72];
    __shared__ bf16 Bs[64][72];
    const int tid  = threadIdx.x;
    const int lane = tid & 63;
    const int wave = tid >> 6;
    const int l15  = lane & 15;
    const int l4   = lane >> 4;
    const int m0   = blockIdx.x * 64;
    const int n0   = blockIdx.y * 64;

    f32x4 acc[4] = {};

    for (int kt = 0; kt < DM; kt += 64) {
        #pragma unroll
        for (int i = 0; i < 4; ++i) {
            const int q   = tid + i * 256;
            const int row = q >> 4;
            const int kq  = (q & 15) * 4;
            bf16x4 av;
            if (A_IS_BF16) {
                av = *(const bf16x4*)((const bf16*)Ap + (size_t)(m0 + row) * DM + kt + kq);
            } else {
                const float4 v = *(const float4*)((const float*)Ap + (size_t)(m0 + row) * DM + kt + kq);
                av[0] = (bf16)v.x; av[1] = (bf16)v.y; av[2] = (bf16)v.z; av[3] = (bf16)v.w;
            }
            *(bf16x4*)&As[row][kq] = av;
            const float4 w = *(const float4*)(W + (size_t)(n0 + row) * DM + kt + kq);
            bf16x4 bv;
            bv[0] = (bf16)w.x; bv[1] = (bf16)w.y; bv[2] = (bf16)w.z; bv[3] = (bf16)w.w;
            *(bf16x4*)&Bs[row][kq] = bv;
        }
        __syncthreads();
        #pragma unroll
        for (int ks = 0; ks < 64; ks += 32) {
            const bf16x8 a = *(const bf16x8*)&As[wave * 16 + l15][ks + 8 * l4];
            #pragma unroll
            for (int n = 0; n < 4; ++n) {
                const bf16x8 b = *(const bf16x8*)&Bs[n * 16 + l15][ks + 8 * l4];
                acc[n] = mfma16(a, b, acc[n]);
            }
        }
        __syncthreads();
    }

    #pragma unroll
    for (int n = 0; n < 4; ++n) {
        const int col = n0 + n * 16 + l15;
        const float bv = bias[col];
        #pragma unroll
        for (int r = 0; r < 4; ++r) {
            const int m = m0 + wave * 16 + l4 * 4 + r;
            float v = acc[n][r] + bv;
            if (shift) v += shift[(m / ROWS_PER_B) * DM + col];
            if (TRANS_OUT) {
                ((bf16*)Out)[((size_t)(m / ROWS_PER_B) * DM + col) * ROWS_PER_B + (m % ROWS_PER_B)] = (bf16)v;
            } else if (OUT_F32) {
                ((float*)Out)[(size_t)m * DM + col] = v;
            } else {
                ((bf16*)Out)[(size_t)m * DM + col] = (bf16)v;
            }
        }
    }
}

// ---------------------------------------------------------------------------
// Flash attention, occupancy-fixed: grid (G/16, H, B) = 2048 blocks, 4 waves.
// All 4 waves share the SAME 16 q-rows; wave w covers s in [w*1024,(w+1)*1024).
// Per-wave online softmax; partials (m,l,acc) merged in LDS at the end.
// LDS: P buffers (4 x 16 x 76 bf16, 9.7KB) unioned with merge buffer (16.9KB).
// P stride 76 bf16 = 38 dwords (38%4==2): rows +-4/8/12 land on distinct banks.
// ---------------------------------------------------------------------------
__global__ __launch_bounds__(256, 8) void attn_kernel(
    const bf16* __restrict__ Qb, const bf16* __restrict__ Kb,
    const bf16* __restrict__ Vt, const int* __restrict__ mask,
    const void* __restrict__ cisv, const int* __restrict__ cis_flag,
    bf16* __restrict__ AO)
{
    __shared__ __align__(16) char smem_raw[17408];
    bf16 (*P)[16][76] = (bf16 (*)[16][76])smem_raw;   // [wave][row][col]
    float* MB = (float*)smem_raw;                     // M[4][16] | L[4][16] | ACC[64][64]

    const int tid  = threadIdx.x;
    const int lane = tid & 63;
    const int wave = tid >> 6;
    const int l15  = lane & 15;
    const int l4   = lane >> 4;
    const int b = blockIdx.z, h = blockIdx.y;
    const int g0 = blockIdx.x * 16;
    const float scale = 0.125f;  // 1/sqrt(64), TEMPERATURE=1
    const int cis_is_byte = cis_flag[0];
    const unsigned char* cis8  = (const unsigned char*)cisv;
    const int*           cis32 = (const int*)cisv;

    const bf16* qrow = Qb + (size_t)(b * G_LEN + g0 + l15) * DM + h * DK + 8 * l4;
    const bf16x8 q0 = *(const bf16x8*)qrow;
    const bf16x8 q1 = *(const bf16x8*)(qrow + 32);

    const int*  maskb = mask + b * S_LEN;
    const bf16* Kbase = Kb + (size_t)b * S_LEN * DM + h * DK;
    const bf16* Vbase = Vt + (size_t)(b * NH + h) * DK * S_LEN;

    f32x4 acc[4] = {};
    float mrow[4] = {-1e30f, -1e30f, -1e30f, -1e30f};
    float lrow[4] = {0.f, 0.f, 0.f, 0.f};

    const int sbeg = wave * (S_LEN / 4);
    const int send = sbeg + (S_LEN / 4);

    for (int s0 = sbeg; s0 < send; s0 += 64) {
        // ---- scores: 16 x 64 tile via 8 MFMAs
        f32x4 c[4];
        #pragma unroll
        for (int sub = 0; sub < 4; ++sub) {
            const bf16* krow = Kbase + (size_t)(s0 + sub * 16 + l15) * DM + 8 * l4;
            const bf16x8 k0 = *(const bf16x8*)krow;
            const bf16x8 k1 = *(const bf16x8*)(krow + 32);
            f32x4 t = {0.f, 0.f, 0.f, 0.f};
            t = mfma16(q0, k0, t);
            t = mfma16(q1, k1, t);
            c[sub] = t;
        }
        // ---- masks: combined keep = mask[b][s] & cis[g][s] (both 0/1)
        int mv[4];
        #pragma unroll
        for (int sub = 0; sub < 4; ++sub) mv[sub] = maskb[s0 + sub * 16 + l15];
        int cv[4][4];
        if (cis_is_byte) {
            #pragma unroll
            for (int sub = 0; sub < 4; ++sub)
                #pragma unroll
                for (int r = 0; r < 4; ++r)
                    cv[sub][r] = (int)cis8[(size_t)(g0 + l4 * 4 + r) * S_LEN + s0 + sub * 16 + l15];
        } else {
            #pragma unroll
            for (int sub = 0; sub < 4; ++sub)
                #pragma unroll
                for (int r = 0; r < 4; ++r)
                    cv[sub][r] = cis32[(size_t)(g0 + l4 * 4 + r) * S_LEN + s0 + sub * 16 + l15];
        }

        // ---- online softmax per q-row (rows live in 16-lane groups)
        float pv[4][4];
        #pragma unroll
        for (int r = 0; r < 4; ++r) {
            float sc[4];
            float tm = -1e30f;
            #pragma unroll
            for (int sub = 0; sub < 4; ++sub) {
                const float v = ((mv[sub] & cv[sub][r]) != 0) ? c[sub][r] * scale : -1e30f;
                sc[sub] = v;
                tm = fmaxf(tm, v);
            }
            #pragma unroll
            for (int off = 1; off < 16; off <<= 1) tm = fmaxf(tm, __shfl_xor(tm, off));
            const float mn = fmaxf(mrow[r], tm);
            const float sf = __expf(mrow[r] - mn);
            mrow[r] = mn;
            float ps = 0.f;
            #pragma unroll
            for (int sub = 0; sub < 4; ++sub) {
                // masked entries: sc-mn <= -1e29 -> v_exp underflows to exactly 0.
                // (an all-masked prefix self-corrects: the next real tile's sf=exp(-1e30-mn)=0
                //  wipes the bogus acc/l; a row masked across ALL of S has probability 0.)
                const float p = __expf(sc[sub] - mn);
                pv[sub][r] = p;
                ps += p;
            }
            #pragma unroll
            for (int off = 1; off < 16; off <<= 1) ps += __shfl_xor(ps, off);
            lrow[r] = lrow[r] * sf + ps;
            #pragma unroll
            for (int n = 0; n < 4; ++n) acc[n][r] *= sf;
        }

        // ---- P -> LDS transpose (per-wave buffer; same-wave LDS ops are ordered)
        #pragma unroll
        for (int sub = 0; sub < 4; ++sub)
            #pragma unroll
            for (int r = 0; r < 4; ++r)
                P[wave][l4 * 4 + r][sub * 16 + l15] = (bf16)pv[sub][r];

        asm volatile("s_waitcnt lgkmcnt(0)" ::: "memory");
        __builtin_amdgcn_sched_barrier(0);

        // ---- PV: out[16][64] += P[16x64] * V[64x64]
        const bf16x8 pa0 = *(const bf16x8*)&P[wave][l15][8 * l4];
        const bf16x8 pa1 = *(const bf16x8*)&P[wave][l15][32 + 8 * l4];
        #pragma unroll
        for (int n = 0; n < 4; ++n) {
            const bf16* vrow = Vbase + (size_t)(n * 16 + l15) * S_LEN + s0 + 8 * l4;
            const bf16x8 v0 = *(const bf16x8*)vrow;
            const bf16x8 v1 = *(const bf16x8*)(vrow + 32);
            acc[n] = mfma16(pa0, v0, acc[n]);
            acc[n] = mfma16(pa1, v1, acc[n]);
        }
    }

    // ---- merge the 4 per-wave partials in LDS (reuses the P region) ----
    __syncthreads();   // everyone done with their P buffer
    #pragma unroll
    for (int r = 0; r < 4; ++r) {
        const int row = l4 * 4 + r;
        #pragma unroll
        for (int n = 0; n < 4; ++n)
            MB[128 + (wave * 16 + row) * 64 + n * 16 + l15] = acc[n][r];
        if (l15 == 0) {
            MB[wave * 16 + row]      = mrow[r];
            MB[64 + wave * 16 + row] = lrow[r];
        }
    }
    __syncthreads();

    #pragma unroll
    for (int i = 0; i < 4; ++i) {
        const int idx = tid + i * 256;
        const int row = idx >> 6;
        const int d   = idx & 63;
        float mx = MB[row];
        #pragma unroll
        for (int c = 1; c < 4; ++c) mx = fmaxf(mx, MB[c * 16 + row]);
        float wl = 0.f, o = 0.f;
        #pragma unroll
        for (int c = 0; c < 4; ++c) {
            const float wc = __expf(MB[c * 16 + row] - mx);
            wl += wc * MB[64 + c * 16 + row];
            o  += wc * MB[128 + (c * 16 + row) * 64 + d];
        }
        const float inv = wl > 0.f ? 1.f / wl : 0.f;
        AO[(size_t)(b * G_LEN + g0 + row) * DM + h * DK + d] = (bf16)(o * inv);
    }
}

// ---------------------------------------------------------------------------
// Row LayerNorm: one block per row (512 cols), 256 threads.
// ---------------------------------------------------------------------------
__global__ __launch_bounds__(256) void out_ln(
    const float* __restrict__ Y, const float* __restrict__ gam,
    const float* __restrict__ bet, float* __restrict__ out)
{
    const int row = blockIdx.x;
    const int tid = threadIdx.x;
    const float x0 = Y[(size_t)row * DM + tid];
    const float x1 = Y[(size_t)row * DM + 256 + tid];
    float s  = x0 + x1;
    float sq = x0 * x0 + x1 * x1;
    #pragma unroll
    for (int off = 1; off < 64; off <<= 1) {
        s  += __shfl_xor(s, off);
        sq += __shfl_xor(sq, off);
    }
    __shared__ float ss[4], ssq[4];
    const int wave = tid >> 6;
    if ((tid & 63) == 0) { ss[wave] = s; ssq[wave] = sq; }
    __syncthreads();
    s  = ss[0] + ss[1] + ss[2] + ss[3];
    sq = ssq[0] + ssq[1] + ssq[2] + ssq[3];
    const float mu  = s * (1.f / 512.f);
    const float var = sq * (1.f / 512.f) - mu * mu;
    const float rs  = rsqrtf(var + 1e-5f);
    out[(size_t)row * DM + tid]       = (x0 - mu) * rs * gam[tid] + bet[tid];
    out[(size_t)row * DM + 256 + tid] = (x1 - mu) * rs * gam[tid + 256] + bet[tid + 256];
}

// ---------------------------------------------------------------------------
extern "C" void kernel_launch(void* const* d_in, const int* in_sizes, int n_in,
                              void* d_out, int out_size, void* d_ws, size_t ws_size,
                              hipStream_t stream) {
    const float* queries     = (const float*)d_in[0];   // [4,1024,512]
    const float* keys_values = (const float*)d_in[1];   // [4,4096,512]
    const float* dq          = (const float*)d_in[2];   // [4,1,512]
    const float* dk          = (const float*)d_in[3];   // [4,1,512]
    const int*   mask        = (const int*)d_in[4];     // [4,4096]
    const void*  cis         = d_in[5];                 // [1024,4096] bool (dtype detected)
    const float* wq_w = (const float*)d_in[6];
    const float* wq_b = (const float*)d_in[7];
    const float* wk_w = (const float*)d_in[8];
    const float* wk_b = (const float*)d_in[9];
    const float* wv_w = (const float*)d_in[10];
    const float* wv_b = (const float*)d_in[11];
    const float* wo_w = (const float*)d_in[12];
    const float* wo_b = (const float*)d_in[13];
    const float* ln_g = (const float*)d_in[14];
    const float* ln_b = (const float*)d_in[15];
    float* out = (float*)d_out;

    char* ws = (char*)d_ws;
    bf16*  Qbf = (bf16*)(ws);                                   //  4 MB [4096,512]
    bf16*  Kbf = (bf16*)(ws + (4u << 20));                      // 16 MB [16384,512]
    bf16*  Vt  = (bf16*)(ws + (20u << 20));                     // 16 MB [4,8,64,4096]
    bf16*  AO  = (bf16*)(ws + (36u << 20));                     //  4 MB [4096,512]
    float* Yw  = (float*)(ws + (40u << 20));                    //  8 MB [4096,512]
    int*   cisflag = (int*)(ws + (48u << 20));                  //  4 B

    detect_cis<<<1, 64, 0, stream>>>((const unsigned char*)cis, cisflag);

    // Projections (f32 -> bf16 MFMA GEMM, conversion fused in staging)
    gemm_proj<0, 0, 0, 1024><<<dim3(64, 8),  256, 0, stream>>>(queries,     wq_w, wq_b, dq,      Qbf);
    gemm_proj<0, 0, 0, 4096><<<dim3(256, 8), 256, 0, stream>>>(keys_values, wk_w, wk_b, dk,      Kbf);
    gemm_proj<0, 1, 0, 4096><<<dim3(256, 8), 256, 0, stream>>>(keys_values, wv_w, wv_b, nullptr, Vt);

    // Fused masked flash attention (in-block S-split x4 for occupancy)
    attn_kernel<<<dim3(64, 8, 4), 256, 0, stream>>>(Qbf, Kbf, Vt, mask, cis, cisflag, AO);

    // Output projection (bf16 A) -> f32 scratch
    gemm_proj<1, 0, 1, 1024><<<dim3(64, 8),  256, 0, stream>>>(AO, wo_w, wo_b, nullptr, Yw);

    // LayerNorm -> d_out
    out_ln<<<4096, 256, 0, stream>>>(Yw, ln_g, ln_b, out);
}

// Round 4
// 409.221 us; speedup vs baseline: 1.4814x; 1.4814x over previous
//
#include <hip/hip_runtime.h>
#include <stdint.h>
#include <stddef.h>

typedef __bf16 bf16;
typedef __bf16 bf16x4 __attribute__((ext_vector_type(4)));
typedef __bf16 bf16x8 __attribute__((ext_vector_type(8)));
typedef float f32x4 __attribute__((ext_vector_type(4)));

#define BATCH 4
#define G_LEN 1024
#define S_LEN 4096
#define DM 512
#define NH 8
#define DK 64

__device__ __forceinline__ f32x4 mfma16(bf16x8 a, bf16x8 b, f32x4 c) {
    return __builtin_amdgcn_mfma_f32_16x16x32_bf16(a, b, c, 0, 0, 0);
}

// ---------------------------------------------------------------------------
// cis dtype detection (bool vs int32) — see round 1 notes. flag=1 -> bytes.
// ---------------------------------------------------------------------------
__global__ void detect_cis(const unsigned char* __restrict__ cis, int* __restrict__ flag) {
    int any = 0;
    for (int i = threadIdx.x; i < 16384; i += 64)
        any |= cis[4 * i + 1];
    #pragma unroll
    for (int off = 1; off < 64; off <<= 1) any |= __shfl_xor(any, off);
    if (threadIdx.x == 0) flag[0] = (any != 0) ? 1 : 0;
}

// ---------------------------------------------------------------------------
// GEMM: Y[m][n] = sum_k X[m][k]*W[n][k] + bias[n] (+ shift[batch(m)][n])
// ---------------------------------------------------------------------------
template<int A_IS_BF16, int TRANS_OUT, int OUT_F32, int ROWS_PER_B>
__global__ __launch_bounds__(256) void gemm_proj(
    const void* __restrict__ Ap, const float* __restrict__ W,
    const float* __restrict__ bias, const float* __restrict__ shift,
    void* __restrict__ Out)
{
    __shared__ bf16 As[64][72];
    __shared__ bf16 Bs[64][72];
    const int tid  = threadIdx.x;
    const int lane = tid & 63;
    const int wave = tid >> 6;
    const int l15  = lane & 15;
    const int l4   = lane >> 4;
    const int m0   = blockIdx.x * 64;
    const int n0   = blockIdx.y * 64;

    f32x4 acc[4] = {};

    for (int kt = 0; kt < DM; kt += 64) {
        #pragma unroll
        for (int i = 0; i < 4; ++i) {
            const int q   = tid + i * 256;
            const int row = q >> 4;
            const int kq  = (q & 15) * 4;
            bf16x4 av;
            if (A_IS_BF16) {
                av = *(const bf16x4*)((const bf16*)Ap + (size_t)(m0 + row) * DM + kt + kq);
            } else {
                const float4 v = *(const float4*)((const float*)Ap + (size_t)(m0 + row) * DM + kt + kq);
                av[0] = (bf16)v.x; av[1] = (bf16)v.y; av[2] = (bf16)v.z; av[3] = (bf16)v.w;
            }
            *(bf16x4*)&As[row][kq] = av;
            const float4 w = *(const float4*)(W + (size_t)(n0 + row) * DM + kt + kq);
            bf16x4 bv;
            bv[0] = (bf16)w.x; bv[1] = (bf16)w.y; bv[2] = (bf16)w.z; bv[3] = (bf16)w.w;
            *(bf16x4*)&Bs[row][kq] = bv;
        }
        __syncthreads();
        #pragma unroll
        for (int ks = 0; ks < 64; ks += 32) {
            const bf16x8 a = *(const bf16x8*)&As[wave * 16 + l15][ks + 8 * l4];
            #pragma unroll
            for (int n = 0; n < 4; ++n) {
                const bf16x8 b = *(const bf16x8*)&Bs[n * 16 + l15][ks + 8 * l4];
                acc[n] = mfma16(a, b, acc[n]);
            }
        }
        __syncthreads();
    }

    #pragma unroll
    for (int n = 0; n < 4; ++n) {
        const int col = n0 + n * 16 + l15;
        const float bv = bias[col];
        #pragma unroll
        for (int r = 0; r < 4; ++r) {
            const int m = m0 + wave * 16 + l4 * 4 + r;
            float v = acc[n][r] + bv;
            if (shift) v += shift[(m / ROWS_PER_B) * DM + col];
            if (TRANS_OUT) {
                ((bf16*)Out)[((size_t)(m / ROWS_PER_B) * DM + col) * ROWS_PER_B + (m % ROWS_PER_B)] = (bf16)v;
            } else if (OUT_F32) {
                ((float*)Out)[(size_t)m * DM + col] = v;
            } else {
                ((bf16*)Out)[(size_t)m * DM + col] = (bf16)v;
            }
        }
    }
}

// ---------------------------------------------------------------------------
// Flash attention: grid (G/16, H, B) = 2048 blocks, 4 waves.
// All 4 waves share the SAME 16 q-rows; wave w covers s in [w*1024,(w+1)*1024).
// Per-wave online softmax; partials (m,l,acc) merged in LDS at the end.
// launch_bounds(256,4): 128 VGPR budget — the (256,8) variant spilled ~1.8GB
// of scratch traffic per dispatch (round 3 post-mortem) and was HBM-bound.
// ---------------------------------------------------------------------------
__global__ __launch_bounds__(256, 4) void attn_kernel(
    const bf16* __restrict__ Qb, const bf16* __restrict__ Kb,
    const bf16* __restrict__ Vt, const int* __restrict__ mask,
    const void* __restrict__ cisv, const int* __restrict__ cis_flag,
    bf16* __restrict__ AO)
{
    __shared__ __align__(16) char smem_raw[17408];
    bf16 (*P)[16][76] = (bf16 (*)[16][76])smem_raw;   // [wave][row][col]
    float* MB = (float*)smem_raw;                     // M[4][16] | L[4][16] | ACC[64][64]

    const int tid  = threadIdx.x;
    const int lane = tid & 63;
    const int wave = tid >> 6;
    const int l15  = lane & 15;
    const int l4   = lane >> 4;
    const int b = blockIdx.z, h = blockIdx.y;
    const int g0 = blockIdx.x * 16;
    const float scale = 0.125f;  // 1/sqrt(64), TEMPERATURE=1
    const int cis_is_byte = cis_flag[0];
    const unsigned char* cis8  = (const unsigned char*)cisv;
    const int*           cis32 = (const int*)cisv;

    const bf16* qrow = Qb + (size_t)(b * G_LEN + g0 + l15) * DM + h * DK + 8 * l4;
    const bf16x8 q0 = *(const bf16x8*)qrow;
    const bf16x8 q1 = *(const bf16x8*)(qrow + 32);

    const int*  maskb = mask + b * S_LEN;
    const bf16* Kbase = Kb + (size_t)b * S_LEN * DM + h * DK;
    const bf16* Vbase = Vt + (size_t)(b * NH + h) * DK * S_LEN;

    f32x4 acc[4] = {};
    float mrow[4] = {-1e30f, -1e30f, -1e30f, -1e30f};
    float lrow[4] = {0.f, 0.f, 0.f, 0.f};

    const int sbeg = wave * (S_LEN / 4);
    const int send = sbeg + (S_LEN / 4);

    for (int s0 = sbeg; s0 < send; s0 += 64) {
        // ---- scores: 16 x 64 tile via 8 MFMAs
        f32x4 c[4];
        #pragma unroll
        for (int sub = 0; sub < 4; ++sub) {
            const bf16* krow = Kbase + (size_t)(s0 + sub * 16 + l15) * DM + 8 * l4;
            const bf16x8 k0 = *(const bf16x8*)krow;
            const bf16x8 k1 = *(const bf16x8*)(krow + 32);
            f32x4 t = {0.f, 0.f, 0.f, 0.f};
            t = mfma16(q0, k0, t);
            t = mfma16(q1, k1, t);
            c[sub] = t;
        }
        // ---- masks: combined keep = mask[b][s] & cis[g][s] (both 0/1)
        int mv[4];
        #pragma unroll
        for (int sub = 0; sub < 4; ++sub) mv[sub] = maskb[s0 + sub * 16 + l15];
        int cv[4][4];
        if (cis_is_byte) {
            #pragma unroll
            for (int sub = 0; sub < 4; ++sub)
                #pragma unroll
                for (int r = 0; r < 4; ++r)
                    cv[sub][r] = (int)cis8[(size_t)(g0 + l4 * 4 + r) * S_LEN + s0 + sub * 16 + l15];
        } else {
            #pragma unroll
            for (int sub = 0; sub < 4; ++sub)
                #pragma unroll
                for (int r = 0; r < 4; ++r)
                    cv[sub][r] = cis32[(size_t)(g0 + l4 * 4 + r) * S_LEN + s0 + sub * 16 + l15];
        }

        // ---- online softmax per q-row (rows live in 16-lane groups)
        float pv[4][4];
        #pragma unroll
        for (int r = 0; r < 4; ++r) {
            float sc[4];
            float tm = -1e30f;
            #pragma unroll
            for (int sub = 0; sub < 4; ++sub) {
                const float v = ((mv[sub] & cv[sub][r]) != 0) ? c[sub][r] * scale : -1e30f;
                sc[sub] = v;
                tm = fmaxf(tm, v);
            }
            #pragma unroll
            for (int off = 1; off < 16; off <<= 1) tm = fmaxf(tm, __shfl_xor(tm, off));
            const float mn = fmaxf(mrow[r], tm);
            const float sf = __expf(mrow[r] - mn);
            mrow[r] = mn;
            float ps = 0.f;
            #pragma unroll
            for (int sub = 0; sub < 4; ++sub) {
                const float p = __expf(sc[sub] - mn);  // masked -> exact 0 underflow
                pv[sub][r] = p;
                ps += p;
            }
            #pragma unroll
            for (int off = 1; off < 16; off <<= 1) ps += __shfl_xor(ps, off);
            lrow[r] = lrow[r] * sf + ps;
            #pragma unroll
            for (int n = 0; n < 4; ++n) acc[n][r] *= sf;
        }

        // ---- P -> LDS transpose (per-wave buffer; same-wave LDS ops are ordered)
        #pragma unroll
        for (int sub = 0; sub < 4; ++sub)
            #pragma unroll
            for (int r = 0; r < 4; ++r)
                P[wave][l4 * 4 + r][sub * 16 + l15] = (bf16)pv[sub][r];

        asm volatile("s_waitcnt lgkmcnt(0)" ::: "memory");
        __builtin_amdgcn_sched_barrier(0);

        // ---- PV: out[16][64] += P[16x64] * V[64x64]
        const bf16x8 pa0 = *(const bf16x8*)&P[wave][l15][8 * l4];
        const bf16x8 pa1 = *(const bf16x8*)&P[wave][l15][32 + 8 * l4];
        #pragma unroll
        for (int n = 0; n < 4; ++n) {
            const bf16* vrow = Vbase + (size_t)(n * 16 + l15) * S_LEN + s0 + 8 * l4;
            const bf16x8 v0 = *(const bf16x8*)vrow;
            const bf16x8 v1 = *(const bf16x8*)(vrow + 32);
            acc[n] = mfma16(pa0, v0, acc[n]);
            acc[n] = mfma16(pa1, v1, acc[n]);
        }
    }

    // ---- merge the 4 per-wave partials in LDS (reuses the P region) ----
    __syncthreads();   // everyone done with their P buffer
    #pragma unroll
    for (int r = 0; r < 4; ++r) {
        const int row = l4 * 4 + r;
        #pragma unroll
        for (int n = 0; n < 4; ++n)
            MB[128 + (wave * 16 + row) * 64 + n * 16 + l15] = acc[n][r];
        if (l15 == 0) {
            MB[wave * 16 + row]      = mrow[r];
            MB[64 + wave * 16 + row] = lrow[r];
        }
    }
    __syncthreads();

    #pragma unroll
    for (int i = 0; i < 4; ++i) {
        const int idx = tid + i * 256;
        const int row = idx >> 6;
        const int d   = idx & 63;
        float mx = MB[row];
        #pragma unroll
        for (int c = 1; c < 4; ++c) mx = fmaxf(mx, MB[c * 16 + row]);
        float wl = 0.f, o = 0.f;
        #pragma unroll
        for (int c = 0; c < 4; ++c) {
            const float wc = __expf(MB[c * 16 + row] - mx);
            wl += wc * MB[64 + c * 16 + row];
            o  += wc * MB[128 + (c * 16 + row) * 64 + d];
        }
        const float inv = wl > 0.f ? 1.f / wl : 0.f;
        AO[(size_t)(b * G_LEN + g0 + row) * DM + h * DK + d] = (bf16)(o * inv);
    }
}

// ---------------------------------------------------------------------------
// Row LayerNorm: one block per row (512 cols), 256 threads.
// ---------------------------------------------------------------------------
__global__ __launch_bounds__(256) void out_ln(
    const float* __restrict__ Y, const float* __restrict__ gam,
    const float* __restrict__ bet, float* __restrict__ out)
{
    const int row = blockIdx.x;
    const int tid = threadIdx.x;
    const float x0 = Y[(size_t)row * DM + tid];
    const float x1 = Y[(size_t)row * DM + 256 + tid];
    float s  = x0 + x1;
    float sq = x0 * x0 + x1 * x1;
    #pragma unroll
    for (int off = 1; off < 64; off <<= 1) {
        s  += __shfl_xor(s, off);
        sq += __shfl_xor(sq, off);
    }
    __shared__ float ss[4], ssq[4];
    const int wave = tid >> 6;
    if ((tid & 63) == 0) { ss[wave] = s; ssq[wave] = sq; }
    __syncthreads();
    s  = ss[0] + ss[1] + ss[2] + ss[3];
    sq = ssq[0] + ssq[1] + ssq[2] + ssq[3];
    const float mu  = s * (1.f / 512.f);
    const float var = sq * (1.f / 512.f) - mu * mu;
    const float rs  = rsqrtf(var + 1e-5f);
    out[(size_t)row * DM + tid]       = (x0 - mu) * rs * gam[tid] + bet[tid];
    out[(size_t)row * DM + 256 + tid] = (x1 - mu) * rs * gam[tid + 256] + bet[tid + 256];
}

// ---------------------------------------------------------------------------
extern "C" void kernel_launch(void* const* d_in, const int* in_sizes, int n_in,
                              void* d_out, int out_size, void* d_ws, size_t ws_size,
                              hipStream_t stream) {
    const float* queries     = (const float*)d_in[0];   // [4,1024,512]
    const float* keys_values = (const float*)d_in[1];   // [4,4096,512]
    const float* dq          = (const float*)d_in[2];   // [4,1,512]
    const float* dk          = (const float*)d_in[3];   // [4,1,512]
    const int*   mask        = (const int*)d_in[4];     // [4,4096]
    const void*  cis         = d_in[5];                 // [1024,4096] bool (dtype detected)
    const float* wq_w = (const float*)d_in[6];
    const float* wq_b = (const float*)d_in[7];
    const float* wk_w = (const float*)d_in[8];
    const float* wk_b = (const float*)d_in[9];
    const float* wv_w = (const float*)d_in[10];
    const float* wv_b = (const float*)d_in[11];
    const float* wo_w = (const float*)d_in[12];
    const float* wo_b = (const float*)d_in[13];
    const float* ln_g = (const float*)d_in[14];
    const float* ln_b = (const float*)d_in[15];
    float* out = (float*)d_out;

    char* ws = (char*)d_ws;
    bf16*  Qbf = (bf16*)(ws);                                   //  4 MB [4096,512]
    bf16*  Kbf = (bf16*)(ws + (4u << 20));                      // 16 MB [16384,512]
    bf16*  Vt  = (bf16*)(ws + (20u << 20));                     // 16 MB [4,8,64,4096]
    bf16*  AO  = (bf16*)(ws + (36u << 20));                     //  4 MB [4096,512]
    float* Yw  = (float*)(ws + (40u << 20));                    //  8 MB [4096,512]
    int*   cisflag = (int*)(ws + (48u << 20));                  //  4 B

    detect_cis<<<1, 64, 0, stream>>>((const unsigned char*)cis, cisflag);

    // Projections (f32 -> bf16 MFMA GEMM, conversion fused in staging)
    gemm_proj<0, 0, 0, 1024><<<dim3(64, 8),  256, 0, stream>>>(queries,     wq_w, wq_b, dq,      Qbf);
    gemm_proj<0, 0, 0, 4096><<<dim3(256, 8), 256, 0, stream>>>(keys_values, wk_w, wk_b, dk,      Kbf);
    gemm_proj<0, 1, 0, 4096><<<dim3(256, 8), 256, 0, stream>>>(keys_values, wv_w, wv_b, nullptr, Vt);

    // Fused masked flash attention (in-block S-split x4 for occupancy)
    attn_kernel<<<dim3(64, 8, 4), 256, 0, stream>>>(Qbf, Kbf, Vt, mask, cis, cisflag, AO);

    // Output projection (bf16 A) -> f32 scratch
    gemm_proj<1, 0, 1, 1024><<<dim3(64, 8),  256, 0, stream>>>(AO, wo_w, wo_b, nullptr, Yw);

    // LayerNorm -> d_out
    out_ln<<<4096, 256, 0, stream>>>(Yw, ln_g, ln_b, out);
}